// Round 2
// baseline (528.424 us; speedup 1.0000x reference)
//
#include <hip/hip_runtime.h>
#include <stdint.h>

typedef unsigned short u16;
typedef unsigned int   u32;

typedef short s8v __attribute__((ext_vector_type(8)));
typedef short s4v __attribute__((ext_vector_type(4)));
typedef float f4v __attribute__((ext_vector_type(4)));

struct __align__(8) US4 { u16 x, y, z, w; };

__device__ __forceinline__ u16 f2bf(float f) {
    union { float f; u32 u; } v; v.f = f;
    u32 u = v.u;
    return (u16)((u + 0x7fffu + ((u >> 16) & 1u)) >> 16);
}

// 16x16x16 bf16 MFMA: registered builtin name (gfx90a+, valid on gfx950)
#define MFMA16(a, b, c) __builtin_amdgcn_mfma_f32_16x16x16bf16_1k((a), (b), (c), 0, 0, 0)
// 16x16x32 bf16 MFMA (gfx950)
#define MFMA32(a, b, c) __builtin_amdgcn_mfma_f32_16x16x32_bf16((a), (b), (c), 0, 0, 0)

// ---------------------------------------------------------------------------
// Pack kernel: weights -> bf16 MFMA A-fragment order; rel bias -> C-frag order
//   pkQ[((mt*8+ks)*64+lane)*8+j] = bf16(qkv_w[(ks*32+quad*8+j)*768 + mt*16+c])
//   pkP analogous for proj_w (256x256)
//   biasP[((h*16+mt*4+nt)*64+lane)*4+r] = table[ridx[query*64+key]*16+h]
//      with key = mt*16+quad*4+r, query = nt*16+c
// ---------------------------------------------------------------------------
__global__ void pack_kernel(const float* __restrict__ qkv_w, const float* __restrict__ proj_w,
                            const float* __restrict__ table, const int* __restrict__ ridx,
                            u16* __restrict__ pkQ, u16* __restrict__ pkP, float* __restrict__ biasP)
{
    int tid = blockIdx.x * 256 + threadIdx.x;
    if (tid < 24576) {
        int g = tid;
        int lane = g & 63, ks = (g >> 6) & 7, mt = g >> 9;
        int quad = lane >> 4, c = lane & 15;
        union { u16 h[8]; s8v v; } tmp;
#pragma unroll
        for (int j = 0; j < 8; ++j) {
            int kk = ks * 32 + quad * 8 + j;
            tmp.h[j] = f2bf(qkv_w[kk * 768 + mt * 16 + c]);
        }
        *(s8v*)&pkQ[g * 8] = tmp.v;
    } else if (tid < 32768) {
        int g = tid - 24576;
        int lane = g & 63, ks = (g >> 6) & 7, mt = g >> 9;
        int quad = lane >> 4, c = lane & 15;
        union { u16 h[8]; s8v v; } tmp;
#pragma unroll
        for (int j = 0; j < 8; ++j) {
            int kk = ks * 32 + quad * 8 + j;
            tmp.h[j] = f2bf(proj_w[kk * 256 + mt * 16 + c]);
        }
        *(s8v*)&pkP[g * 8] = tmp.v;
    } else if (tid < 49152) {
        int g = tid - 32768;
        int h = g >> 10, rest = (g >> 6) & 15, lane = g & 63;
        int mt = rest >> 2, nt = rest & 3;
        int quad = lane >> 4, c = lane & 15;
        int query = nt * 16 + c;
#pragma unroll
        for (int r = 0; r < 4; ++r) {
            int key = mt * 16 + quad * 4 + r;
            biasP[g * 4 + r] = table[ridx[query * 64 + key] * 16 + h];
        }
    }
}

// ---------------------------------------------------------------------------
// Main fused kernel: one block per 8x8 window. 1024 threads = 16 waves.
// ---------------------------------------------------------------------------
__global__ __launch_bounds__(1024)
void attn_win_kernel(const float* __restrict__ X,
                     const float* __restrict__ pre_g, const float* __restrict__ pre_b,
                     const float* __restrict__ post_g, const float* __restrict__ post_b,
                     const float* __restrict__ qkv_b, const float* __restrict__ proj_b,
                     const u16* __restrict__ pkQ, const u16* __restrict__ pkP,
                     const float* __restrict__ biasP,
                     float* __restrict__ out)
{
    // LDS carve-out (138,752 B total):
    //   [     0, 33792) xnS  [64][264] bf16   (later: attnout, same layout)
    //   [ 33792, 67584) qS   [64][264] bf16   token-major
    //   [ 67584,101376) kS   [64][264] bf16   token-major
    //   [101376,138240) vS   [256][72] bf16   channel-major (v^T)
    //   xf (fp32 [256][68]) aliases kS+vS during load & epilogue phases
    //   [138240,138752) st   [64][2] fp32 LN stats
    __shared__ __align__(16) unsigned char smem[138752];
    u16*   xnS = (u16*)smem;
    u16*   qS  = xnS + 16896;
    u16*   kS  = qS + 16896;
    u16*   vS  = kS + 16896;
    float* xf  = (float*)(smem + 67584);
    float* st  = (float*)(smem + 138240);

    const int tid  = threadIdx.x;
    const int w    = tid >> 6;    // wave id 0..15
    const int l    = tid & 63;    // lane
    const int quad = l >> 4;
    const int c    = l & 15;

    const int win = blockIdx.x;
    const int bb = win >> 10;
    const int wh = (win >> 5) & 31;
    const int ww = win & 31;
    const size_t base = (((size_t)bb * 256) * 256 + wh * 8) * 256 + ww * 8;

    // ---- phase 0a: coalesced window load; stash residual in regs; stage to xf (channel-major) ----
    f4v xreg[4];
    {
        const int ch0 = (tid >> 4);
        const int t0  = (tid & 15) * 4;
        const int r0 = t0 >> 3, c0 = t0 & 7;
#pragma unroll
        for (int it = 0; it < 4; ++it) {
            int ch = it * 64 + ch0;
            f4v v = *(const f4v*)(X + base + (size_t)ch * 65536 + r0 * 256 + c0);
            xreg[it] = v;
            *(f4v*)&xf[ch * 68 + t0] = v;
        }
    }
    __syncthreads();

    // ---- phase 0b: pre-LN stats (wave w -> tokens 4w..4w+3, one per quad) ----
    {
        int tk = w * 4 + quad;
        float s = 0.f, ss = 0.f;
#pragma unroll
        for (int j = 0; j < 16; ++j) {
            float x = xf[(c + 16 * j) * 68 + tk];
            s += x; ss += x * x;
        }
#pragma unroll
        for (int m = 1; m < 16; m <<= 1) { s += __shfl_xor(s, m, 64); ss += __shfl_xor(ss, m, 64); }
        float mean = s * (1.f / 256.f);
        float var  = ss * (1.f / 256.f) - mean * mean;
        float rstd = rsqrtf(var + 1e-5f);
        if (c == 0) { st[tk * 2] = mean; st[tk * 2 + 1] = rstd; }
    }
    __syncthreads();

    // ---- phase 0c: xn = LN(xw)*g+b  -> bf16 token-major ----
    {
        int t = l;               // with 16 waves each wave covers its 16-channel strip
        int chg = w * 16;
        float mean = st[t * 2], rstd = st[t * 2 + 1];
        union { u16 h[16]; s8v v[2]; } tmp;
#pragma unroll
        for (int j = 0; j < 16; ++j) {
            int ch = chg + j;
            float x = xf[ch * 68 + t];
            tmp.h[j] = f2bf((x - mean) * rstd * pre_g[ch] + pre_b[ch]);
        }
        *(s8v*)&xnS[t * 264 + chg]     = tmp.v[0];
        *(s8v*)&xnS[t * 264 + chg + 8] = tmp.v[1];
    }
    __syncthreads();

    // ---- phase 1: QKV^T GEMM (M=768 channels, N=64 tokens, K=256), wave w -> m-tiles 3w..3w+2 ----
    {
        f4v acc[3][4];
#pragma unroll
        for (int i = 0; i < 3; ++i)
#pragma unroll
            for (int nt = 0; nt < 4; ++nt) acc[i][nt] = 0.f;

        const s8v* A = (const s8v*)pkQ;
#pragma unroll
        for (int ks = 0; ks < 8; ++ks) {
            s8v bfr[4];
#pragma unroll
            for (int nt = 0; nt < 4; ++nt)
                bfr[nt] = *(const s8v*)&xnS[(nt * 16 + c) * 264 + ks * 32 + quad * 8];
#pragma unroll
            for (int i = 0; i < 3; ++i) {
                int mt = w * 3 + i;
                s8v afr = A[(mt * 8 + ks) * 64 + l];
#pragma unroll
                for (int nt = 0; nt < 4; ++nt)
                    acc[i][nt] = MFMA32(afr, bfr[nt], acc[i][nt]);
            }
        }
        // epilogue: bias, l2norm for q/k, transpose-store for v
#pragma unroll
        for (int i = 0; i < 3; ++i) {
            int mt = w * 3 + i;
            float b0 = qkv_b[mt * 16 + quad * 4 + 0];
            float b1 = qkv_b[mt * 16 + quad * 4 + 1];
            float b2 = qkv_b[mt * 16 + quad * 4 + 2];
            float b3 = qkv_b[mt * 16 + quad * 4 + 3];
#pragma unroll
            for (int nt = 0; nt < 4; ++nt) {
                f4v a = acc[i][nt];
                a[0] += b0; a[1] += b1; a[2] += b2; a[3] += b3;
                int tok = nt * 16 + c;
                if (mt < 32) {
                    // q or k: l2-normalize over this head's 16 dims (= this m-tile's rows)
                    float ss = a[0]*a[0] + a[1]*a[1] + a[2]*a[2] + a[3]*a[3];
                    ss += __shfl_xor(ss, 16, 64);
                    ss += __shfl_xor(ss, 32, 64);
                    float inv = 1.0f / fmaxf(sqrtf(ss), 1e-12f);
                    US4 pk;
                    pk.x = f2bf(a[0] * inv); pk.y = f2bf(a[1] * inv);
                    pk.z = f2bf(a[2] * inv); pk.w = f2bf(a[3] * inv);
                    int off = tok * 264 + (mt & 15) * 16 + quad * 4;
                    if (mt < 16) *(US4*)&qS[off] = pk;
                    else         *(US4*)&kS[off] = pk;
                } else {
                    // v: pair-swap (lane^1) to write 2 tokens per b32, channel-major v^T
                    float p0 = __shfl_xor(a[0], 1, 64), p1 = __shfl_xor(a[1], 1, 64);
                    float p2 = __shfl_xor(a[2], 1, 64), p3 = __shfl_xor(a[3], 1, 64);
                    int chb = (mt - 32) * 16 + quad * 4;
                    if ((l & 1) == 0) {
                        *(u32*)&vS[(chb + 0) * 72 + tok] = (u32)f2bf(a[0]) | ((u32)f2bf(p0) << 16);
                        *(u32*)&vS[(chb + 1) * 72 + tok] = (u32)f2bf(a[1]) | ((u32)f2bf(p1) << 16);
                    } else {
                        *(u32*)&vS[(chb + 2) * 72 + tok - 1] = (u32)f2bf(p2) | ((u32)f2bf(a[2]) << 16);
                        *(u32*)&vS[(chb + 3) * 72 + tok - 1] = (u32)f2bf(p3) | ((u32)f2bf(a[3]) << 16);
                    }
                }
            }
        }
    }
    __syncthreads();

    // ---- phase 2: attention, wave w = head h. S^T = K·Q^T so softmax is in-lane+quad,
    //      and P^T C-fragments feed PV B-operand directly from registers. ----
    {
        const int h = w;
        s4v kfr[4], vfr[4];
#pragma unroll
        for (int mt = 0; mt < 4; ++mt)
            kfr[mt] = *(const s4v*)&kS[(mt * 16 + c) * 264 + h * 16 + quad * 4];
#pragma unroll
        for (int kt = 0; kt < 4; ++kt)
            vfr[kt] = *(const s4v*)&vS[(h * 16 + c) * 72 + kt * 16 + quad * 4];

        const f4v* BP = (const f4v*)biasP;
#pragma unroll
        for (int half = 0; half < 2; ++half) {
            f4v sT[4][2];
#pragma unroll
            for (int nt2 = 0; nt2 < 2; ++nt2) {
                int nt = half * 2 + nt2;
                s4v qfr = *(const s4v*)&qS[(nt * 16 + c) * 264 + h * 16 + quad * 4];
#pragma unroll
                for (int mt = 0; mt < 4; ++mt) {
                    f4v bv = BP[(h * 16 + mt * 4 + nt) * 64 + l];  // bias in C-layout
                    sT[mt][nt2] = MFMA16(kfr[mt], qfr, bv);
                }
            }
#pragma unroll
            for (int nt2 = 0; nt2 < 2; ++nt2) {
                int nt = half * 2 + nt2;
                float mx = -1e30f;
#pragma unroll
                for (int mt = 0; mt < 4; ++mt)
#pragma unroll
                    for (int r = 0; r < 4; ++r) mx = fmaxf(mx, sT[mt][nt2][r]);
                mx = fmaxf(mx, __shfl_xor(mx, 16, 64));
                mx = fmaxf(mx, __shfl_xor(mx, 32, 64));
                float p[16];
                float sum = 0.f;
#pragma unroll
                for (int mt = 0; mt < 4; ++mt)
#pragma unroll
                    for (int r = 0; r < 4; ++r) {
                        float e = __expf(sT[mt][nt2][r] - mx);
                        p[mt * 4 + r] = e; sum += e;
                    }
                sum += __shfl_xor(sum, 16, 64);
                sum += __shfl_xor(sum, 32, 64);
                float inv = 1.f / sum;
                f4v o = 0.f;
#pragma unroll
                for (int kt = 0; kt < 4; ++kt) {
                    s4v pv = { (short)f2bf(p[kt * 4 + 0] * inv), (short)f2bf(p[kt * 4 + 1] * inv),
                               (short)f2bf(p[kt * 4 + 2] * inv), (short)f2bf(p[kt * 4 + 3] * inv) };
                    o = MFMA16(vfr[kt], pv, o);   // out^T[d][query] += v^T · P^T
                }
                US4 ov; ov.x = f2bf(o[0]); ov.y = f2bf(o[1]); ov.z = f2bf(o[2]); ov.w = f2bf(o[3]);
                *(US4*)&xnS[(nt * 16 + c) * 264 + h * 16 + quad * 4] = ov;  // attnout (aliases xn)
            }
        }
    }
    __syncthreads();

    // ---- phase 3: proj^T GEMM (M=256 c_out, N=64 tokens, K=256), wave w -> m-tile w ----
    {
        f4v acc[4];
#pragma unroll
        for (int nt = 0; nt < 4; ++nt) acc[nt] = 0.f;
        const s8v* A = (const s8v*)pkP;
#pragma unroll
        for (int ks = 0; ks < 8; ++ks) {
            s8v afr = A[(w * 8 + ks) * 64 + l];
#pragma unroll
            for (int nt = 0; nt < 4; ++nt) {
                s8v bfr = *(const s8v*)&xnS[(nt * 16 + c) * 264 + ks * 32 + quad * 8];
                acc[nt] = MFMA32(afr, bfr, acc[nt]);
            }
        }
        float b0 = proj_b[w * 16 + quad * 4 + 0];
        float b1 = proj_b[w * 16 + quad * 4 + 1];
        float b2 = proj_b[w * 16 + quad * 4 + 2];
        float b3 = proj_b[w * 16 + quad * 4 + 3];
#pragma unroll
        for (int nt = 0; nt < 4; ++nt) {
            int tok = nt * 16 + c;
            int chb = w * 16 + quad * 4;
            xf[(chb + 0) * 68 + tok] = acc[nt][0] + b0;
            xf[(chb + 1) * 68 + tok] = acc[nt][1] + b1;
            xf[(chb + 2) * 68 + tok] = acc[nt][2] + b2;
            xf[(chb + 3) * 68 + tok] = acc[nt][3] + b3;
        }
    }
    __syncthreads();

    // ---- phase 4: residual add from registers ----
    {
        const int ch0 = (tid >> 4);
        const int t0  = (tid & 15) * 4;
#pragma unroll
        for (int it = 0; it < 4; ++it) {
            int ch = it * 64 + ch0;
            f4v v = *(f4v*)&xf[ch * 68 + t0];
            v += xreg[it];
            *(f4v*)&xf[ch * 68 + t0] = v;
        }
    }
    __syncthreads();

    // ---- phase 4b: post-LN stats ----
    {
        int tk = w * 4 + quad;
        float s = 0.f, ss = 0.f;
#pragma unroll
        for (int j = 0; j < 16; ++j) {
            float x = xf[(c + 16 * j) * 68 + tk];
            s += x; ss += x * x;
        }
#pragma unroll
        for (int m = 1; m < 16; m <<= 1) { s += __shfl_xor(s, m, 64); ss += __shfl_xor(ss, m, 64); }
        float mean = s * (1.f / 256.f);
        float var  = ss * (1.f / 256.f) - mean * mean;
        float rstd = rsqrtf(var + 1e-5f);
        if (c == 0) { st[tk * 2] = mean; st[tk * 2 + 1] = rstd; }
    }
    __syncthreads();

    // ---- phase 5: y = x + LN(x)*g+b, coalesced store ----
    {
        const int ch0 = (tid >> 4);
        const int t0  = (tid & 15) * 4;
        const int r0 = t0 >> 3, c0 = t0 & 7;
#pragma unroll
        for (int it = 0; it < 4; ++it) {
            int ch = it * 64 + ch0;
            f4v x = *(f4v*)&xf[ch * 68 + t0];
            float g = post_g[ch], b = post_b[ch];
            f4v y;
#pragma unroll
            for (int j = 0; j < 4; ++j) {
                float mean = st[(t0 + j) * 2], rstd = st[(t0 + j) * 2 + 1];
                y[j] = x[j] + (x[j] - mean) * rstd * g + b;
            }
            *(f4v*)(out + base + (size_t)ch * 65536 + r0 * 256 + c0) = y;
        }
    }
}

extern "C" void kernel_launch(void* const* d_in, const int* in_sizes, int n_in,
                              void* d_out, int out_size, void* d_ws, size_t ws_size,
                              hipStream_t stream)
{
    const float* X      = (const float*)d_in[0];
    const float* pre_g  = (const float*)d_in[1];
    const float* pre_b  = (const float*)d_in[2];
    const float* post_g = (const float*)d_in[3];
    const float* post_b = (const float*)d_in[4];
    const float* qkv_w  = (const float*)d_in[5];
    const float* qkv_b  = (const float*)d_in[6];
    const float* proj_w = (const float*)d_in[7];
    const float* proj_b = (const float*)d_in[8];
    const float* table  = (const float*)d_in[9];
    const int*   ridx   = (const int*)d_in[10];

    u16*   pkQ   = (u16*)d_ws;                          // 393,216 B
    u16*   pkP   = (u16*)((char*)d_ws + 393216);        // 131,072 B
    float* biasP = (float*)((char*)d_ws + 524288);      // 262,144 B

    pack_kernel<<<192, 256, 0, stream>>>(qkv_w, proj_w, table, ridx, pkQ, pkP, biasP);
    attn_win_kernel<<<2048, 1024, 0, stream>>>(X, pre_g, pre_b, post_g, post_b,
                                               qkv_b, proj_b, pkQ, pkP, biasP,
                                               (float*)d_out);
}